// Round 6
// baseline (439.709 us; speedup 1.0000x reference)
//
#include <hip/hip_runtime.h>
#include <cstdint>
#include <cstddef>

// Problem constants (match reference)
#define BTOT    4096
#define SRCLEN  128
#define INDIM   16
#define HDIM    64
#define SEQLEN  100
#define MEANS_N (BTOT * SEQLEN * 4)   // 1638400

// ---------- helpers ----------
__device__ __forceinline__ float sigmoidf_(float x) { return 1.0f / (1.0f + __expf(-x)); }
__device__ __forceinline__ float tanhf_(float x) {
    float e = __expf(2.0f * x);
    return 1.0f - 2.0f / (e + 1.0f);
}
__device__ __forceinline__ float gelu_exact(float x) {
    return 0.5f * x * (1.0f + erff(x * 0.70710678118654752440f));
}

// lgkm-only barrier: drains LDS ops but NOT outstanding global loads/stores.
__device__ __forceinline__ void lgkm_barrier() {
    asm volatile("s_waitcnt lgkmcnt(0)" ::: "memory");
    __builtin_amdgcn_s_barrier();
}

// ---------- bf16 split helpers (bf16x3 emulated-fp32 MFMA) ----------
typedef __attribute__((ext_vector_type(8))) short s8v;          // 8 bf16 — MFMA A/B frag
typedef __attribute__((ext_vector_type(4))) float f4v;          // 4 fp32 — MFMA C/D frag
typedef __attribute__((ext_vector_type(4))) unsigned int u4v;   // 4 u32 — packed h quad

__device__ __forceinline__ unsigned short f2bf(float x) {  // RTNE float -> bf16 bits
    unsigned u = __float_as_uint(x);
    unsigned r = (u + 0x7FFFu + ((u >> 16) & 1u)) >> 16;
    return (unsigned short)r;
}
__device__ __forceinline__ float bf2f(unsigned short b) {
    return __uint_as_float(((unsigned)b) << 16);
}
__device__ __forceinline__ unsigned rtne_hi_bits(float x) {
    unsigned u = __float_as_uint(x);
    return (u + 0x7FFFu + ((u >> 16) & 1u)) & 0xFFFF0000u;
}
// full-RTNE split (prologue / weights)
__device__ __forceinline__ void split2(float4 a, float4 b, s8v& hi, s8v& lo) {
    float v[8] = {a.x, a.y, a.z, a.w, b.x, b.y, b.z, b.w};
    #pragma unroll
    for (int j = 0; j < 8; ++j) {
        unsigned short h = f2bf(v[j]);
        hi[j] = (short)h;
        lo[j] = (short)f2bf(v[j] - bf2f(h));
    }
}
__device__ __forceinline__ void split8(const float* v, s8v& hi, s8v& lo) {
    #pragma unroll
    for (int j = 0; j < 8; ++j) {
        unsigned short h = f2bf(v[j]);
        hi[j] = (short)h;
        lo[j] = (short)f2bf(v[j] - bf2f(h));
    }
}
// fast hot-loop split: RTNE hi + truncated lo (err <= 2^-17 |x|)
__device__ __forceinline__ void split2_fast(float4 a, float4 b, s8v& hi, s8v& lo) {
    float v[8] = {a.x, a.y, a.z, a.w, b.x, b.y, b.z, b.w};
    #pragma unroll
    for (int j = 0; j < 8; ++j) {
        unsigned hb = rtne_hi_bits(v[j]);
        hi[j] = (short)(hb >> 16);
        float lof = v[j] - __uint_as_float(hb);
        lo[j] = (short)(__float_as_uint(lof) >> 16);
    }
}
__device__ __forceinline__ void load_bfrag(const float* p, s8v& hi, s8v& lo) {
    float4 a = *(const float4*)p;
    float4 b = *(const float4*)(p + 4);
    split2(a, b, hi, lo);
}
// pack h as (hi16 << 16) | lo16 (hi = RTNE, lo = truncated residual)
__device__ __forceinline__ unsigned pack_hl(float h) {
    unsigned hb = rtne_hi_bits(h);
    float lof = h - __uint_as_float(hb);
    return hb | (__float_as_uint(lof) >> 16);
}
// unpack 8 packed u32 -> hi s8v + lo s8v (v_perm_b32)
__device__ __forceinline__ void unpack8(u4v pa, u4v pb, s8v& hi, s8v& lo) {
    union { s8v v; unsigned w[4]; } H, L;
    H.w[0] = __builtin_amdgcn_perm(pa.y, pa.x, 0x07060302u);
    H.w[1] = __builtin_amdgcn_perm(pa.w, pa.z, 0x07060302u);
    H.w[2] = __builtin_amdgcn_perm(pb.y, pb.x, 0x07060302u);
    H.w[3] = __builtin_amdgcn_perm(pb.w, pb.z, 0x07060302u);
    L.w[0] = __builtin_amdgcn_perm(pa.y, pa.x, 0x05040100u);
    L.w[1] = __builtin_amdgcn_perm(pa.w, pa.z, 0x05040100u);
    L.w[2] = __builtin_amdgcn_perm(pb.y, pb.x, 0x05040100u);
    L.w[3] = __builtin_amdgcn_perm(pb.w, pb.z, 0x05040100u);
    hi = H.v; lo = L.v;
}

#define MFMA16(a, b, c) __builtin_amdgcn_mfma_f32_16x16x32_bf16((a), (b), (c), 0, 0, 0)

// =====================================================================
// Encoder GRU via MFMA (bf16x3).  Grid 256 WGs x 256 thr (4 waves, 1/SIMD).
// Wave w owns all 3 gates for units w*16..w*16+15 -> ONE handoff per step:
// h broadcast through packed-u32 LDS (conflict-free b32 writes, b128 reads
// + v_perm unpack).  MFMA chains split 3-way (hh/hl/lh) for ILP.
// One lgkm-only barrier per step (ping-pong buffers make it sufficient).
// =====================================================================
__global__ __launch_bounds__(256, 1) void enc_mfma_kernel(
    const float* __restrict__ x,
    const float* __restrict__ Wih, const float* __restrict__ bih,
    const float* __restrict__ Whh, const float* __restrict__ bhh,
    float* __restrict__ enc_h)
{
    const int tid  = threadIdx.x;
    const int lane = tid & 63;
    const int w    = tid >> 6;     // wave 0..3
    const int col  = lane & 15;
    const int q    = lane >> 4;
    const int u    = w * 16 + col; // gate-local unit 0..63
    const int b0   = blockIdx.x * 16;

    // packed h: [buf][batch 16][unit 64 (+4 pad)] as (hi16|lo16)
    __shared__ __align__(16) unsigned int hpk[2][16][68];

    for (int i = tid; i < 16 * 68; i += 256)   // zero buf 0 (h0 = 0)
        ((unsigned int*)hpk)[i] = 0u;

    const s8v z8 = {0, 0, 0, 0, 0, 0, 0, 0};
    const f4v z4 = {0.0f, 0.0f, 0.0f, 0.0f};

    // ---- B fragments (weights) in VGPRs; chunks: h[0:32), h[32:64), x ----
    s8v brh[3], brl[3], bzh[3], bzl[3], bnhh[2], bnhl[2], bnxh, bnxl;
    load_bfrag(Whh + (size_t)u * 64 + q * 8,              brh[0], brl[0]);
    load_bfrag(Whh + (size_t)u * 64 + 32 + q * 8,         brh[1], brl[1]);
    load_bfrag(Whh + (size_t)(64 + u) * 64 + q * 8,       bzh[0], bzl[0]);
    load_bfrag(Whh + (size_t)(64 + u) * 64 + 32 + q * 8,  bzh[1], bzl[1]);
    load_bfrag(Whh + (size_t)(128 + u) * 64 + q * 8,      bnhh[0], bnhl[0]);
    load_bfrag(Whh + (size_t)(128 + u) * 64 + 32 + q * 8, bnhh[1], bnhl[1]);
    if (q < 2) {
        load_bfrag(Wih + (size_t)u * 16 + q * 8,         brh[2], brl[2]);
        load_bfrag(Wih + (size_t)(64 + u) * 16 + q * 8,  bzh[2], bzl[2]);
        load_bfrag(Wih + (size_t)(128 + u) * 16 + q * 8, bnxh, bnxl);
    } else {
        brh[2] = z8; brl[2] = z8; bzh[2] = z8; bzl[2] = z8; bnxh = z8; bnxl = z8;
    }

    const float br  = bih[u] + bhh[u];
    const float bz  = bih[u + 64] + bhh[u + 64];
    const float bnx = bih[u + 128];
    const float bnh = bhh[u + 128];

    s8v xh = z8, xl = z8;
    if (q < 2) {
        const float* xp = x + ((size_t)(b0 + col) * SRCLEN + 0) * INDIM + q * 8;
        split2_fast(*(const float4*)xp, *(const float4*)(xp + 4), xh, xl);
    }

    f4v hold = z4;
    __syncthreads();

    int cur = 0;
    for (int t = 0; t < SRCLEN; ++t) {
        float4 nx0, nx1;
        if (q < 2) {   // clamped prefetch; never drained at the lgkm barrier
            const int tt = (t + 1 < SRCLEN) ? (t + 1) : (SRCLEN - 1);
            const float* xp = x + ((size_t)(b0 + col) * SRCLEN + tt) * INDIM + q * 8;
            nx0 = *(const float4*)xp;
            nx1 = *(const float4*)(xp + 4);
        }

        // A-frags: packed h -> b128 reads + v_perm unpack
        const u4v pa0 = *(const u4v*)&hpk[cur][col][q * 8];
        const u4v pb0 = *(const u4v*)&hpk[cur][col][q * 8 + 4];
        const u4v pa1 = *(const u4v*)&hpk[cur][col][32 + q * 8];
        const u4v pb1 = *(const u4v*)&hpk[cur][col][32 + q * 8 + 4];
        s8v ah0, al0, ah1, al1;
        unpack8(pa0, pb0, ah0, al0);
        unpack8(pa1, pb1, ah1, al1);

        // r-gate: 3 independent 3-chains (hh / hl / lh)
        f4v rA = MFMA16(ah0, brh[0], z4);
        f4v rB = MFMA16(ah0, brl[0], z4);
        f4v rC = MFMA16(al0, brh[0], z4);
        f4v zA = MFMA16(ah0, bzh[0], z4);
        f4v zB = MFMA16(ah0, bzl[0], z4);
        f4v zC = MFMA16(al0, bzh[0], z4);
        f4v nA = MFMA16(ah0, bnhh[0], z4);
        f4v nB = MFMA16(ah0, bnhl[0], z4);
        f4v nC = MFMA16(al0, bnhh[0], z4);
        rA = MFMA16(ah1, brh[1], rA);
        rB = MFMA16(ah1, brl[1], rB);
        rC = MFMA16(al1, brh[1], rC);
        zA = MFMA16(ah1, bzh[1], zA);
        zB = MFMA16(ah1, bzl[1], zB);
        zC = MFMA16(al1, bzh[1], zC);
        nA = MFMA16(ah1, bnhh[1], nA);
        nB = MFMA16(ah1, bnhl[1], nB);
        nC = MFMA16(al1, bnhh[1], nC);
        rA = MFMA16(xh, brh[2], rA);
        rB = MFMA16(xh, brl[2], rB);
        rC = MFMA16(xl, brh[2], rC);
        zA = MFMA16(xh, bzh[2], zA);
        zB = MFMA16(xh, bzl[2], zB);
        zC = MFMA16(xl, bzh[2], zC);
        f4v accnx = MFMA16(xh, bnxh, z4);
        accnx = MFMA16(xh, bnxl, accnx);
        accnx = MFMA16(xl, bnxh, accnx);

        const f4v accr  = rA + rB + rC;
        const f4v accz  = zA + zB + zC;
        const f4v accnh = nA + nB + nC;

        const int nxt = cur ^ 1;
        unsigned int* hw = &hpk[nxt][q * 4][u];
        #pragma unroll
        for (int i = 0; i < 4; ++i) {
            float r  = sigmoidf_(accr[i] + br);
            float zz = sigmoidf_(accz[i] + bz);
            float n  = tanhf_(accnx[i] + bnx + r * (accnh[i] + bnh));
            float h  = (1.0f - zz) * n + zz * hold[i];
            hold[i]  = h;
            hw[i * 68] = pack_hl(h);
        }
        lgkm_barrier();   // h_{t+1} visible; WAR on cur safe (reads precede barrier)

        if (q < 2) split2_fast(nx0, nx1, xh, xl);
        cur = nxt;
    }

    #pragma unroll
    for (int i = 0; i < 4; ++i)
        enc_h[(size_t)(b0 + q * 4 + i) * HDIM + u] = hold[i];
}

// =====================================================================
// Decoder GRU via MFMA, out-projection folded (Wcomb = Wih@outW merged
// into r/z; i_n separate).  Same single-barrier packed-h structure.
// Wave 0 computes o_{t-1} (+6 MFMA, issued first) and streams to dec_o.
// Grid 256 WGs x 256 thr.
// =====================================================================
__global__ __launch_bounds__(256, 1) void dec_mfma_kernel(
    const float* __restrict__ trg,
    const float* __restrict__ Wih, const float* __restrict__ bih,
    const float* __restrict__ Whh, const float* __restrict__ bhh,
    const float* __restrict__ outW, const float* __restrict__ outb,
    const float* __restrict__ embW, const float* __restrict__ embb,
    const float* __restrict__ enc_h,
    float* __restrict__ dec_o)
{
    const int tid  = threadIdx.x;
    const int lane = tid & 63;
    const int w    = tid >> 6;
    const int col  = lane & 15;
    const int q    = lane >> 4;
    const int u    = w * 16 + col;
    const int b0   = blockIdx.x * 16;

    __shared__ __align__(16) unsigned int hpk[2][16][68];
    __shared__ float outW_l[16][64];
    __shared__ float init_l[16][16];

    // ---- stage LDS: outW, init_in, packed h0 ----
    for (int i = tid; i < 16 * 64; i += 256) outW_l[i >> 6][i & 63] = outW[i];
    {
        int b = tid >> 4, jj = tid & 15;
        float s = embb[jj];
        #pragma unroll
        for (int s4 = 0; s4 < 4; ++s4)
            s = fmaf(embW[jj * 4 + s4], trg[(size_t)(b0 + b) * 4 + s4], s);
        init_l[b][jj] = s;
    }
    {
        int idx = tid * 4;
        int bb = idx >> 6, uu = idx & 63;
        float4 v = *(const float4*)(enc_h + (size_t)(b0 + bb) * HDIM + uu);
        float vv[4] = {v.x, v.y, v.z, v.w};
        #pragma unroll
        for (int j = 0; j < 4; ++j)
            hpk[0][bb][uu + j] = pack_hl(vv[j]);
    }
    f4v hold;
    #pragma unroll
    for (int i = 0; i < 4; ++i)
        hold[i] = enc_h[(size_t)(b0 + q * 4 + i) * HDIM + u];

    __syncthreads();

    const f4v z4 = {0.0f, 0.0f, 0.0f, 0.0f};
    const s8v z8 = {0, 0, 0, 0, 0, 0, 0, 0};

    // ---- fp32 weight rows for this lane's k-slice ----
    float wh_r[16], wh_z[16], wh_n[16];
    #pragma unroll
    for (int c = 0; c < 2; ++c)
        #pragma unroll
        for (int jj = 0; jj < 8; ++jj) {
            int k = c * 32 + q * 8 + jj;
            wh_r[c * 8 + jj] = Whh[(size_t)u * 64 + k];
            wh_z[c * 8 + jj] = Whh[(size_t)(64 + u) * 64 + k];
            wh_n[c * 8 + jj] = Whh[(size_t)(128 + u) * 64 + k];
        }
    float wi_r[16], wi_z[16], wi_n[16];
    #pragma unroll
    for (int j = 0; j < 16; ++j) {
        wi_r[j] = Wih[(size_t)u * 16 + j];
        wi_z[j] = Wih[(size_t)(64 + u) * 16 + j];
        wi_n[j] = Wih[(size_t)(128 + u) * 16 + j];
    }

    // ---- Wcomb = Wih @ outW; merge into r/z; i_n separate ----
    float m_r[16], m_z[16], c_in[16];
    #pragma unroll
    for (int c = 0; c < 2; ++c)
        #pragma unroll
        for (int jj = 0; jj < 8; ++jj) {
            int k = c * 32 + q * 8 + jj;
            float sr = 0.0f, sz = 0.0f, sn = 0.0f;
            #pragma unroll
            for (int j = 0; j < 16; ++j) {
                float ow = outW_l[j][k];
                sr = fmaf(wi_r[j], ow, sr);
                sz = fmaf(wi_z[j], ow, sz);
                sn = fmaf(wi_n[j], ow, sn);
            }
            m_r[c * 8 + jj]  = wh_r[c * 8 + jj] + sr;
            m_z[c * 8 + jj]  = wh_z[c * 8 + jj] + sz;
            c_in[c * 8 + jj] = sn;
        }

    // ---- B-frags ----
    s8v mrh[2], mrl[2], mzh[2], mzl[2], cinh[2], cinl[2], hnh[2], hnl[2];
    split8(m_r,      mrh[0],  mrl[0]);  split8(m_r + 8,  mrh[1],  mrl[1]);
    split8(m_z,      mzh[0],  mzl[0]);  split8(m_z + 8,  mzh[1],  mzl[1]);
    split8(c_in,     cinh[0], cinl[0]); split8(c_in + 8, cinh[1], cinl[1]);
    split8(wh_n,     hnh[0],  hnl[0]);  split8(wh_n + 8, hnh[1],  hnl[1]);
    s8v r0h[2], r0l[2], z0h[2], z0l[2];
    split8(wh_r, r0h[0], r0l[0]); split8(wh_r + 8, r0h[1], r0l[1]);
    split8(wh_z, z0h[0], z0l[0]); split8(wh_z + 8, z0h[1], z0l[1]);
    s8v owh[2], owl[2];
    owh[0] = z8; owl[0] = z8; owh[1] = z8; owl[1] = z8;
    float ob = 0.0f;
    if (w == 0) {
        float ov[16];
        #pragma unroll
        for (int c = 0; c < 2; ++c)
            #pragma unroll
            for (int jj = 0; jj < 8; ++jj)
                ov[c * 8 + jj] = outW_l[col][c * 32 + q * 8 + jj];
        split8(ov, owh[0], owl[0]); split8(ov + 8, owh[1], owl[1]);
        ob = outb[col];
    }

    // ---- folded biases ----
    float b_r = bhh[u] + bih[u];
    float b_z = bhh[u + 64] + bih[u + 64];
    float b_in = bih[u + 128];
    const float b_hn = bhh[u + 128];
    #pragma unroll
    for (int j = 0; j < 16; ++j) {
        float obj = outb[j];
        b_r  = fmaf(obj, wi_r[j], b_r);
        b_z  = fmaf(obj, wi_z[j], b_z);
        b_in = fmaf(obj, wi_n[j], b_in);
    }

    // ---- gi0 from init_in ----
    float g_r[4], g_z[4], g_n[4];
    #pragma unroll
    for (int i = 0; i < 4; ++i) {
        float sr = bih[u] + bhh[u];
        float sz = bih[u + 64] + bhh[u + 64];
        float sn = bih[u + 128];
        #pragma unroll
        for (int j = 0; j < 16; ++j) {
            float iv = init_l[q * 4 + i][j];
            sr = fmaf(wi_r[j], iv, sr);
            sz = fmaf(wi_z[j], iv, sz);
            sn = fmaf(wi_n[j], iv, sn);
        }
        g_r[i] = sr; g_z[i] = sz; g_n[i] = sn;
    }

    // ---- step 0: h1 = GRU(h0, init_in), unmerged r/z ----
    {
        const u4v pa0 = *(const u4v*)&hpk[0][col][q * 8];
        const u4v pb0 = *(const u4v*)&hpk[0][col][q * 8 + 4];
        const u4v pa1 = *(const u4v*)&hpk[0][col][32 + q * 8];
        const u4v pb1 = *(const u4v*)&hpk[0][col][32 + q * 8 + 4];
        s8v ah0, al0, ah1, al1;
        unpack8(pa0, pb0, ah0, al0);
        unpack8(pa1, pb1, ah1, al1);

        f4v rA = MFMA16(ah0, r0h[0], z4);
        f4v rB = MFMA16(ah0, r0l[0], z4);
        f4v rC = MFMA16(al0, r0h[0], z4);
        f4v zA = MFMA16(ah0, z0h[0], z4);
        f4v zB = MFMA16(ah0, z0l[0], z4);
        f4v zC = MFMA16(al0, z0h[0], z4);
        f4v nA = MFMA16(ah0, hnh[0], z4);
        f4v nB = MFMA16(ah0, hnl[0], z4);
        f4v nC = MFMA16(al0, hnh[0], z4);
        rA = MFMA16(ah1, r0h[1], rA);
        rB = MFMA16(ah1, r0l[1], rB);
        rC = MFMA16(al1, r0h[1], rC);
        zA = MFMA16(ah1, z0h[1], zA);
        zB = MFMA16(ah1, z0l[1], zB);
        zC = MFMA16(al1, z0h[1], zC);
        nA = MFMA16(ah1, hnh[1], nA);
        nB = MFMA16(ah1, hnl[1], nB);
        nC = MFMA16(al1, hnh[1], nC);
        const f4v ar  = rA + rB + rC;
        const f4v az  = zA + zB + zC;
        const f4v ahn = nA + nB + nC;

        unsigned int* hw = &hpk[1][q * 4][u];
        #pragma unroll
        for (int i = 0; i < 4; ++i) {
            float r  = sigmoidf_(ar[i] + g_r[i]);
            float zz = sigmoidf_(az[i] + g_z[i]);
            float n  = tanhf_(g_n[i] + r * (ahn[i] + b_hn));
            float h  = (1.0f - zz) * n + zz * hold[i];
            hold[i]  = h;
            hw[i * 68] = pack_hl(h);
        }
        lgkm_barrier();
    }

    // ---- steps 1..99 (merged weights); o_{t-1} by wave 0, issued first ----
    for (int t = 1; t < SEQLEN; ++t) {
        const int cur = t & 1;
        const u4v pa0 = *(const u4v*)&hpk[cur][col][q * 8];
        const u4v pb0 = *(const u4v*)&hpk[cur][col][q * 8 + 4];
        const u4v pa1 = *(const u4v*)&hpk[cur][col][32 + q * 8];
        const u4v pb1 = *(const u4v*)&hpk[cur][col][32 + q * 8 + 4];
        s8v ah0, al0, ah1, al1;
        unpack8(pa0, pb0, ah0, al0);
        unpack8(pa1, pb1, ah1, al1);

        if (w == 0) {   // o_{t-1} = h_t @ outW^T + outb
            f4v oA = MFMA16(ah0, owh[0], z4);
            f4v oB = MFMA16(ah0, owl[0], z4);
            f4v oC = MFMA16(al0, owh[0], z4);
            oA = MFMA16(ah1, owh[1], oA);
            oB = MFMA16(ah1, owl[1], oB);
            oC = MFMA16(al1, owh[1], oC);
            const f4v oa = oA + oB + oC;
            #pragma unroll
            for (int i = 0; i < 4; ++i)
                dec_o[(((size_t)(b0 + q * 4 + i) * SEQLEN) + (t - 1)) * INDIM + col] = oa[i] + ob;
        }

        f4v rA = MFMA16(ah0, mrh[0], z4);
        f4v rB = MFMA16(ah0, mrl[0], z4);
        f4v rC = MFMA16(al0, mrh[0], z4);
        f4v zA = MFMA16(ah0, mzh[0], z4);
        f4v zB = MFMA16(ah0, mzl[0], z4);
        f4v zC = MFMA16(al0, mzh[0], z4);
        f4v iA = MFMA16(ah0, cinh[0], z4);
        f4v iB = MFMA16(ah0, cinl[0], z4);
        f4v iC = MFMA16(al0, cinh[0], z4);
        f4v nA = MFMA16(ah0, hnh[0], z4);
        f4v nB = MFMA16(ah0, hnl[0], z4);
        f4v nC = MFMA16(al0, hnh[0], z4);
        rA = MFMA16(ah1, mrh[1], rA);
        rB = MFMA16(ah1, mrl[1], rB);
        rC = MFMA16(al1, mrh[1], rC);
        zA = MFMA16(ah1, mzh[1], zA);
        zB = MFMA16(ah1, mzl[1], zB);
        zC = MFMA16(al1, mzh[1], zC);
        iA = MFMA16(ah1, cinh[1], iA);
        iB = MFMA16(ah1, cinl[1], iB);
        iC = MFMA16(al1, cinh[1], iC);
        nA = MFMA16(ah1, hnh[1], nA);
        nB = MFMA16(ah1, hnl[1], nB);
        nC = MFMA16(al1, hnh[1], nC);
        const f4v ar  = rA + rB + rC;
        const f4v az  = zA + zB + zC;
        const f4v ain = iA + iB + iC;
        const f4v ahn = nA + nB + nC;

        const int nxt = cur ^ 1;
        unsigned int* hw = &hpk[nxt][q * 4][u];
        #pragma unroll
        for (int i = 0; i < 4; ++i) {
            float r  = sigmoidf_(ar[i] + b_r);
            float zz = sigmoidf_(az[i] + b_z);
            float n  = tanhf_(ain[i] + b_in + r * (ahn[i] + b_hn));
            float h  = (1.0f - zz) * n + zz * hold[i];
            hold[i]  = h;
            hw[i * 68] = pack_hl(h);
        }
        lgkm_barrier();
    }

    // ---- epilogue: o_99 = h_100 @ outW^T + outb (buf 0) ----
    if (w == 0) {
        const u4v pa0 = *(const u4v*)&hpk[0][col][q * 8];
        const u4v pb0 = *(const u4v*)&hpk[0][col][q * 8 + 4];
        const u4v pa1 = *(const u4v*)&hpk[0][col][32 + q * 8];
        const u4v pb1 = *(const u4v*)&hpk[0][col][32 + q * 8 + 4];
        s8v ah0, al0, ah1, al1;
        unpack8(pa0, pb0, ah0, al0);
        unpack8(pa1, pb1, ah1, al1);
        f4v oA = MFMA16(ah0, owh[0], z4);
        f4v oB = MFMA16(ah0, owl[0], z4);
        f4v oC = MFMA16(al0, owh[0], z4);
        oA = MFMA16(ah1, owh[1], oA);
        oB = MFMA16(ah1, owl[1], oB);
        oC = MFMA16(al1, owh[1], oC);
        const f4v oa = oA + oB + oC;
        #pragma unroll
        for (int i = 0; i < 4; ++i)
            dec_o[(((size_t)(b0 + q * 4 + i) * SEQLEN) + (SEQLEN - 1)) * INDIM + col] = oa[i] + ob;
    }
}

// =====================================================================
// Heads: 409600 independent rows; one thread per row. (unchanged)
// =====================================================================
__global__ void heads_kernel(
    const float* __restrict__ dec_o,
    const float* __restrict__ mW1, const float* __restrict__ mb1,
    const float* __restrict__ mW2, const float* __restrict__ mb2,
    const float* __restrict__ cW1, const float* __restrict__ cb1,
    const float* __restrict__ cW2, const float* __restrict__ cb2,
    float* __restrict__ out)
{
    const size_t r = (size_t)blockIdx.x * 256 + threadIdx.x;  // 0..409599

    float o16[16];
    {
        const float4* op = (const float4*)(dec_o + r * 16);
        #pragma unroll
        for (int c = 0; c < 4; ++c) {
            float4 v = op[c];
            o16[4 * c + 0] = v.x; o16[4 * c + 1] = v.y;
            o16[4 * c + 2] = v.z; o16[4 * c + 3] = v.w;
        }
    }

    float m[4], cv[10];
    #pragma unroll
    for (int j = 0; j < 4; ++j)  m[j]  = mb2[j];
    #pragma unroll
    for (int j = 0; j < 10; ++j) cv[j] = cb2[j];

    #pragma unroll 8
    for (int hu = 0; hu < 64; ++hu) {
        const float* w1m = mW1 + hu * 16;
        float hm = mb1[hu];
        #pragma unroll
        for (int i = 0; i < 16; ++i) hm = fmaf(w1m[i], o16[i], hm);
        float gm = gelu_exact(hm);
        #pragma unroll
        for (int j = 0; j < 4; ++j) m[j] = fmaf(mW2[j * 64 + hu], gm, m[j]);

        const float* w1c = cW1 + hu * 16;
        float hc = cb1[hu];
        #pragma unroll
        for (int i = 0; i < 16; ++i) hc = fmaf(w1c[i], o16[i], hc);
        float gc = gelu_exact(hc);
        #pragma unroll
        for (int j = 0; j < 10; ++j) cv[j] = fmaf(cW2[j * 64 + hu], gc, cv[j]);
    }

    m[2] = fminf(fmaxf(m[2], -1.0f), 1.0f);
    m[3] = fminf(fmaxf(m[3], -1.0f), 1.0f);

    float* means = out;
    float* covs  = out + MEANS_N;
    #pragma unroll
    for (int j = 0; j < 4; ++j)  means[r * 4 + j]  = m[j];
    #pragma unroll
    for (int j = 0; j < 10; ++j) covs[r * 10 + j]  = cv[j];
}

// =====================================================================
extern "C" void kernel_launch(void* const* d_in, const int* in_sizes, int n_in,
                              void* d_out, int out_size, void* d_ws, size_t ws_size,
                              hipStream_t stream)
{
    const float* x    = (const float*)d_in[0];
    const float* trg  = (const float*)d_in[1];
    const float* eWih = (const float*)d_in[2];
    const float* ebih = (const float*)d_in[3];
    const float* eWhh = (const float*)d_in[4];
    const float* ebhh = (const float*)d_in[5];
    const float* dWih = (const float*)d_in[6];
    const float* dbih = (const float*)d_in[7];
    const float* dWhh = (const float*)d_in[8];
    const float* dbhh = (const float*)d_in[9];
    const float* outW = (const float*)d_in[10];
    const float* outb = (const float*)d_in[11];
    const float* embW = (const float*)d_in[12];
    const float* embb = (const float*)d_in[13];
    const float* mW1  = (const float*)d_in[14];
    const float* mb1  = (const float*)d_in[15];
    const float* mW2  = (const float*)d_in[16];
    const float* mb2  = (const float*)d_in[17];
    const float* cW1  = (const float*)d_in[18];
    const float* cb1  = (const float*)d_in[19];
    const float* cW2  = (const float*)d_in[20];
    const float* cb2  = (const float*)d_in[21];

    float* ws    = (float*)d_ws;
    float* enc_h = ws;                          // 4096*64      = 262144 floats
    float* dec_o = ws + (size_t)BTOT * HDIM;    // 4096*100*16  = 6553600 floats
    float* outp  = (float*)d_out;

    enc_mfma_kernel<<<dim3(BTOT / 16), dim3(256), 0, stream>>>(x, eWih, ebih, eWhh, ebhh, enc_h);
    dec_mfma_kernel<<<dim3(BTOT / 16), dim3(256), 0, stream>>>(trg, dWih, dbih, dWhh, dbhh,
                                                               outW, outb, embW, embb, enc_h, dec_o);
    heads_kernel<<<dim3((BTOT * SEQLEN) / 256), dim3(256), 0, stream>>>(
        dec_o, mW1, mb1, mW2, mb2, cW1, cb1, cW2, cb2, outp);
}